// Round 5
// baseline (1697.057 us; speedup 1.0000x reference)
//
#include <hip/hip_runtime.h>
#include <math.h>

// CapsuleLayer dynamic routing, MI355X fp32. Round 5: B_CHUNK=16 (2x arithmetic
// intensity on the W stream -- R4 counters showed L2-delivery-bound at 21% VALU).
// B=64, In=2048, Din=16, Nc=32, Dc=32, ROUTINGS=3.
// b starts at 0 => logits_t = hat . (v0+..+v_{t-1}); never store b or hat.
// Grid 128 ig x 4 bg = 512 blocks = exactly 2/CU (all co-resident; same-ig
// blocks are 128 apart = same XCD -> W L2 reuse within an XCD).
// VGPR budget: w[16]f4=64 + h[16][4]=64 + acc[16][4]=64 + temps ~= 224 < 256
// cap from __launch_bounds__(256,2). Spill would show as WRITE_SIZE balloon.

#define B_TOT   64
#define IN_CAPS 2048
#define DIN     16
#define NC      32
#define DC      32
#define JD      (NC * DC)                  // 1024
#define B_CHUNK 16
#define I_CHUNK 16
#define N_IG    (IN_CAPS / I_CHUNK)        // 128
#define EPS_SQ  1e-7f
#define SLOT_ELEMS ((size_t)B_TOT * JD)    // 65536 floats = 256 KB

__device__ __forceinline__ float dot4(float4 a, float4 b) {
    return a.x * b.x + a.y * b.y + a.z * b.z + a.w * b.w;
}

// block 256: t = j*8 + dqi; j in [0,32), dqi -> d-quad dq = dqi*4.
template <int PHASE>
__launch_bounds__(256, 2)
__global__ void caps_fused(const float* __restrict__ x,
                           const float* __restrict__ W,
                           const float* __restrict__ vsum,
                           float* __restrict__ P,
                           int slot_mask)
{
    __shared__ float xs[B_CHUNK][DIN];   // 1 KB
    __shared__ float ls[B_CHUNK][NC];    // 2 KB: logits, then c

    const int t  = threadIdx.x;
    const int j  = t >> 3;               // 0..31
    const int dq = (t & 7) * 4;          // 0,4,..,28
    const int ig = blockIdx.x;           // 0..127
    const int b0 = blockIdx.y * B_CHUNK;
    const int i0 = ig * I_CHUNK;

    float acc[B_CHUNK][4];
#pragma unroll
    for (int b = 0; b < B_CHUNK; ++b)
#pragma unroll
        for (int dd = 0; dd < 4; ++dd) acc[b][dd] = 0.f;

#pragma unroll 1
    for (int il = 0; il < I_CHUNK; ++il) {
        const int i = i0 + il;

        __syncthreads();                 // xs/ls safe to rewrite
        {
            const int bl = t >> 4, k = t & 15;   // 256 threads = 16 b x 16 k
            xs[bl][k] = x[((size_t)(b0 + bl) * IN_CAPS + i) * DIN + k];
        }
        __syncthreads();

        // this thread's W slice: (j, dq..dq+3, all 16 k) = 64 contig floats
        const float4* Wp =
            (const float4*)(W + (((size_t)j * IN_CAPS + i) * DC + dq) * DIN);
        float4 w[16];
#pragma unroll
        for (int q = 0; q < 16; ++q) w[q] = Wp[q];

        float h[B_CHUNK][4];             // hat values, live across barriers
#pragma unroll
        for (int b = 0; b < B_CHUNK; ++b) {
            const float4 x0 = *(const float4*)&xs[b][0];   // wave-broadcast reads
            const float4 x1 = *(const float4*)&xs[b][4];
            const float4 x2 = *(const float4*)&xs[b][8];
            const float4 x3 = *(const float4*)&xs[b][12];
#pragma unroll
            for (int dd = 0; dd < 4; ++dd) {
                h[b][dd] = dot4(w[dd * 4 + 0], x0) + dot4(w[dd * 4 + 1], x1)
                         + dot4(w[dd * 4 + 2], x2) + dot4(w[dd * 4 + 3], x3);
            }
        }

        if (PHASE == 0) {
#pragma unroll
            for (int b = 0; b < B_CHUNK; ++b)
#pragma unroll
                for (int dd = 0; dd < 4; ++dd) acc[b][dd] += h[b][dd];
        } else {
            // logits: lp = h . vsum (d-partial), reduced over the 8 dq threads.
            // vsum slice per (b): wave reads contiguous 1 KB -> coalesced, L2-hot.
#pragma unroll
            for (int b = 0; b < B_CHUNK; ++b) {
                const float4 vv =
                    *(const float4*)&vsum[((size_t)(b0 + b) * NC + j) * DC + dq];
                float lp = h[b][0] * vv.x + h[b][1] * vv.y
                         + h[b][2] * vv.z + h[b][3] * vv.w;
                lp += __shfl_xor(lp, 1, 8);
                lp += __shfl_xor(lp, 2, 8);
                lp += __shfl_xor(lp, 4, 8);
                if ((t & 7) == 0) ls[b][j] = lp;
            }
            __syncthreads();

            // softmax over j: 256 threads = 16 b x 16 jj, each handles jj, jj+16
            {
                const int bb = t >> 4;       // 0..15
                const int jj = t & 15;       // 0..15
                const float l0 = ls[bb][jj];
                const float l1 = ls[bb][jj + 16];
                float m = fmaxf(l0, l1);
                m = fmaxf(m, __shfl_xor(m, 1, 16));
                m = fmaxf(m, __shfl_xor(m, 2, 16));
                m = fmaxf(m, __shfl_xor(m, 4, 16));
                m = fmaxf(m, __shfl_xor(m, 8, 16));
                const float e0 = __expf(l0 - m);
                const float e1 = __expf(l1 - m);
                float ssum = e0 + e1;
                ssum += __shfl_xor(ssum, 1, 16);
                ssum += __shfl_xor(ssum, 2, 16);
                ssum += __shfl_xor(ssum, 4, 16);
                ssum += __shfl_xor(ssum, 8, 16);
                const float inv = 1.f / ssum;
                ls[bb][jj]      = e0 * inv;
                ls[bb][jj + 16] = e1 * inv;
            }
            __syncthreads();

            // c-weighted accumulate (h still in registers)
#pragma unroll
            for (int b = 0; b < B_CHUNK; ++b) {
                const float c = ls[b][j];
                acc[b][0] += c * h[b][0];
                acc[b][1] += c * h[b][1];
                acc[b][2] += c * h[b][2];
                acc[b][3] += c * h[b][3];
            }
        }
    }

    const float scale = (PHASE == 0) ? (1.f / NC) : 1.f;
    const int slot = ig & slot_mask;
    float* dst = P + (size_t)slot * SLOT_ELEMS + (size_t)b0 * JD + j * DC + dq;
#pragma unroll
    for (int b = 0; b < B_CHUNK; ++b)
#pragma unroll
        for (int dd = 0; dd < 4; ++dd)
            atomicAdd(dst + (size_t)b * JD + dd, acc[b][dd] * scale);
}

// Sum nparts slots, squash over Dc=32 (32 consecutive lanes = one capsule),
// mode 0: VSUM = v ; 1: VSUM += v ; 2: OUT = v.  zero_after: re-zero P slots.
__global__ void reduce_squash(float* __restrict__ P, int nparts,
                              float* __restrict__ VSUM,
                              float* __restrict__ OUT, int mode, int zero_after)
{
    const int idx = blockIdx.x * blockDim.x + threadIdx.x;  // b*1024 + jd
    float val = 0.f;
    for (int s = 0; s < nparts; ++s)
        val += P[(size_t)s * SLOT_ELEMS + idx];
    if (zero_after) {
        for (int s = 0; s < nparts; ++s)
            P[(size_t)s * SLOT_ELEMS + idx] = 0.f;
    }

    float s2 = val * val;
#pragma unroll
    for (int off = 16; off >= 1; off >>= 1)
        s2 += __shfl_xor(s2, off, 32);
    const float sc = s2 / (1.f + s2) * rsqrtf(s2 + EPS_SQ);
    const float v  = sc * val;
    if (mode == 0)      VSUM[idx] = v;
    else if (mode == 1) VSUM[idx] += v;
    else                OUT[idx] = v;
}

extern "C" void kernel_launch(void* const* d_in, const int* in_sizes, int n_in,
                              void* d_out, int out_size, void* d_ws, size_t ws_size,
                              hipStream_t stream)
{
    const float* x = (const float*)d_in[0];   // [64, 2048, 16]
    const float* W = (const float*)d_in[1];   // [32, 2048, 32, 16]
    float* out = (float*)d_out;               // [64, 32, 32]

    // choose n_slots (pow2) from workspace: P = n_slots*256KB, then VSUM 256KB
    const size_t ws_floats = ws_size / sizeof(float);
    size_t avail = (ws_floats > SLOT_ELEMS) ? ws_floats - SLOT_ELEMS : 0;
    int n_slots = 1;
    while (n_slots < 8 && (size_t)(n_slots * 2) * SLOT_ELEMS <= avail)
        n_slots *= 2;
    const int slot_mask = n_slots - 1;

    float* P    = (float*)d_ws;
    float* VSUM = P + (size_t)n_slots * SLOT_ELEMS;

    const dim3 grid(N_IG, B_TOT / B_CHUNK);   // 128 x 4 = 512 blocks (2/CU)
    const dim3 blk(256);
    const int  rs_grid = (B_TOT * JD) / 256;  // 256

    hipMemsetAsync(P, 0, (size_t)n_slots * SLOT_ELEMS * sizeof(float), stream);

    // iter 0: uniform c = 1/32
    caps_fused<0><<<grid, blk, 0, stream>>>(x, W, nullptr, P, slot_mask);
    reduce_squash<<<rs_grid, 256, 0, stream>>>(P, n_slots, VSUM, out, 0, 1);

    // iter 1: logits = hat . v0
    caps_fused<1><<<grid, blk, 0, stream>>>(x, W, VSUM, P, slot_mask);
    reduce_squash<<<rs_grid, 256, 0, stream>>>(P, n_slots, VSUM, out, 1, 1);

    // iter 2: logits = hat . (v0+v1)
    caps_fused<1><<<grid, blk, 0, stream>>>(x, W, VSUM, P, slot_mask);
    reduce_squash<<<rs_grid, 256, 0, stream>>>(P, n_slots, VSUM, out, 2, 0);
}

// Round 6
// 1640.748 us; speedup vs baseline: 1.0343x; 1.0343x over previous
//
#include <hip/hip_runtime.h>
#include <math.h>

// CapsuleLayer dynamic routing, MI355X fp32. Round 6.
// R5 lesson: compiler caps this kernel at 128 VGPR (launch_bounds ignored above
// that) -> keep B_CHUNK=8 and split W into two 8-float4 halves (demand ~128).
// R4 counters: 297 MB FETCH @1.4 TB/s = whole pass -> fix (a) coalescing via
// swizzled LDS staging of the 64KB W i-tile, (b) within-pass W refetch via
// block swizzle putting all 8 bg-blocks of an ig co-resident on one XCD.

#define B_TOT   64
#define IN_CAPS 2048
#define DIN     16
#define NC      32
#define DC      32
#define JD      (NC * DC)                  // 1024
#define B_CHUNK 8
#define I_CHUNK 16
#define N_IG    (IN_CAPS / I_CHUNK)        // 128
#define EPS_SQ  1e-7f
#define SLOT_ELEMS ((size_t)B_TOT * JD)    // 65536 floats = 256 KB

__device__ __forceinline__ float dot4(float4 a, float4 b) {
    return a.x * b.x + a.y * b.y + a.z * b.z + a.w * b.w;
}

// 1-D grid of 1024 blocks. bid decode: bg=(bid>>3)&7, ig=(bid&7)|((bid>>6)<<3)
// -> same-ig blocks have bids {c,c+8,..,c+56}: co-resident AND bid%8 const
// (same XCD under round-robin dispatch) -> W tile fetched ~once per pass.
// block 256: t = j*8 + dqi; thread's W slice = tile floats [64t, 64t+64).
template <int PHASE>
__launch_bounds__(256, 2)
__global__ void caps_fused(const float* __restrict__ x,
                           const float* __restrict__ W,
                           const float* __restrict__ vsum,
                           float* __restrict__ P,
                           int slot_mask)
{
    // W tile, swizzled: chunk c (=thread) at float4 slot c*17, 16 payload + 1 pad.
    __shared__ float4 wl4[256 * 17];     // 69632 B
    __shared__ float  xs[B_CHUNK][DIN];  // 512 B
    __shared__ float  ls[B_CHUNK][NC];   // 1 KB

    const int t  = threadIdx.x;
    const int j  = t >> 3;               // 0..31
    const int dq = (t & 7) * 4;          // 0,4,..,28

    const int bid = blockIdx.x;          // 0..1023
    const int bg  = (bid >> 3) & 7;
    const int ig  = (bid & 7) | ((bid >> 6) << 3);
    const int b0  = bg * B_CHUNK;
    const int i0  = ig * I_CHUNK;

    const float4* Wg = (const float4*)W;
    const float*  wf = (const float*)wl4;
    const float4* myW = (const float4*)(wf + t * 68);  // 272B-aligned

    float acc[B_CHUNK][4];
#pragma unroll
    for (int b = 0; b < B_CHUNK; ++b)
#pragma unroll
        for (int dd = 0; dd < 4; ++dd) acc[b][dd] = 0.f;

#pragma unroll 1
    for (int il = 0; il < I_CHUNK; ++il) {
        const int i = i0 + il;

        __syncthreads();                 // previous il's LDS reads complete
        if (t < B_CHUNK * DIN) {         // stage x: 128 threads
            const int bl = t >> 4, k = t & 15;
            xs[bl][k] = x[((size_t)(b0 + bl) * IN_CAPS + i) * DIN + k];
        }
        // stage W i-tile (64 KB), fully coalesced: instruction r reads 1 KB/wave
#pragma unroll
        for (int r = 0; r < 16; ++r) {
            const int idx = r * 256 + t;        // tile float4 index
            const int jj  = idx >> 7;           // 128 float4 per j
            const int rem = idx & 127;
            const float4 v = Wg[((size_t)jj * IN_CAPS + i) * (DC * DIN / 4) + rem];
            wl4[(idx >> 4) * 17 + (idx & 15)] = v;   // swizzled store (2-way, free)
        }
        __syncthreads();

        // hat: two halves of 8 float4 W-regs each (VGPR cap 128 -- R5 lesson)
        float h[B_CHUNK][4];
#pragma unroll
        for (int half = 0; half < 2; ++half) {
            float4 w[8];
#pragma unroll
            for (int q = 0; q < 8; ++q) w[q] = myW[half * 8 + q];  // conflict-free
#pragma unroll
            for (int b = 0; b < B_CHUNK; ++b) {
                const float4 x0 = *(const float4*)&xs[b][0];   // broadcast reads
                const float4 x1 = *(const float4*)&xs[b][4];
                const float4 x2 = *(const float4*)&xs[b][8];
                const float4 x3 = *(const float4*)&xs[b][12];
#pragma unroll
                for (int d2 = 0; d2 < 2; ++d2) {
                    h[b][half * 2 + d2] =
                        dot4(w[d2 * 4 + 0], x0) + dot4(w[d2 * 4 + 1], x1) +
                        dot4(w[d2 * 4 + 2], x2) + dot4(w[d2 * 4 + 3], x3);
                }
            }
        }

        if (PHASE == 0) {
#pragma unroll
            for (int b = 0; b < B_CHUNK; ++b)
#pragma unroll
                for (int dd = 0; dd < 4; ++dd) acc[b][dd] += h[b][dd];
        } else {
            // logits: lp = h . vsum, reduced over the 8 dq threads per j
#pragma unroll
            for (int b = 0; b < B_CHUNK; ++b) {
                const float4 vv =
                    *(const float4*)&vsum[((size_t)(b0 + b) * NC + j) * DC + dq];
                float lp = h[b][0] * vv.x + h[b][1] * vv.y
                         + h[b][2] * vv.z + h[b][3] * vv.w;
                lp += __shfl_xor(lp, 1, 8);
                lp += __shfl_xor(lp, 2, 8);
                lp += __shfl_xor(lp, 4, 8);
                if ((t & 7) == 0) ls[b][j] = lp;
            }
            __syncthreads();

            // softmax over j: 256 threads = 8 b x 32 j, one (b,j) each
            {
                const int bb = t >> 5;
                const int jj = t & 31;
                const float l = ls[bb][jj];
                float m = l;
                m = fmaxf(m, __shfl_xor(m, 1, 32));
                m = fmaxf(m, __shfl_xor(m, 2, 32));
                m = fmaxf(m, __shfl_xor(m, 4, 32));
                m = fmaxf(m, __shfl_xor(m, 8, 32));
                m = fmaxf(m, __shfl_xor(m, 16, 32));
                const float e = __expf(l - m);
                float ssum = e;
                ssum += __shfl_xor(ssum, 1, 32);
                ssum += __shfl_xor(ssum, 2, 32);
                ssum += __shfl_xor(ssum, 4, 32);
                ssum += __shfl_xor(ssum, 8, 32);
                ssum += __shfl_xor(ssum, 16, 32);
                ls[bb][jj] = e / ssum;
            }
            __syncthreads();

            // c-weighted accumulate (h in registers across the barriers)
#pragma unroll
            for (int b = 0; b < B_CHUNK; ++b) {
                const float c = ls[b][j];
                acc[b][0] += c * h[b][0];
                acc[b][1] += c * h[b][1];
                acc[b][2] += c * h[b][2];
                acc[b][3] += c * h[b][3];
            }
        }
    }

    const float scale = (PHASE == 0) ? (1.f / NC) : 1.f;
    const int slot = ig & slot_mask;     // = bid&7 & mask -> XCD-local partials
    float* dst = P + (size_t)slot * SLOT_ELEMS + (size_t)b0 * JD + j * DC + dq;
#pragma unroll
    for (int b = 0; b < B_CHUNK; ++b)
#pragma unroll
        for (int dd = 0; dd < 4; ++dd)
            atomicAdd(dst + (size_t)b * JD + dd, acc[b][dd] * scale);
}

// Sum nparts slots, squash over Dc=32 (32 consecutive lanes = one capsule),
// mode 0: VSUM = v ; 1: VSUM += v ; 2: OUT = v.  zero_after: re-zero P slots.
__global__ void reduce_squash(float* __restrict__ P, int nparts,
                              float* __restrict__ VSUM,
                              float* __restrict__ OUT, int mode, int zero_after)
{
    const int idx = blockIdx.x * blockDim.x + threadIdx.x;  // b*1024 + jd
    float val = 0.f;
    for (int s = 0; s < nparts; ++s)
        val += P[(size_t)s * SLOT_ELEMS + idx];
    if (zero_after) {
        for (int s = 0; s < nparts; ++s)
            P[(size_t)s * SLOT_ELEMS + idx] = 0.f;
    }

    float s2 = val * val;
#pragma unroll
    for (int off = 16; off >= 1; off >>= 1)
        s2 += __shfl_xor(s2, off, 32);
    const float sc = s2 / (1.f + s2) * rsqrtf(s2 + EPS_SQ);
    const float v  = sc * val;
    if (mode == 0)      VSUM[idx] = v;
    else if (mode == 1) VSUM[idx] += v;
    else                OUT[idx] = v;
}

extern "C" void kernel_launch(void* const* d_in, const int* in_sizes, int n_in,
                              void* d_out, int out_size, void* d_ws, size_t ws_size,
                              hipStream_t stream)
{
    const float* x = (const float*)d_in[0];   // [64, 2048, 16]
    const float* W = (const float*)d_in[1];   // [32, 2048, 32, 16]
    float* out = (float*)d_out;               // [64, 32, 32]

    // n_slots (pow2, <=8) from workspace: P = n_slots*256KB, then VSUM 256KB
    const size_t ws_floats = ws_size / sizeof(float);
    size_t avail = (ws_floats > SLOT_ELEMS) ? ws_floats - SLOT_ELEMS : 0;
    int n_slots = 1;
    while (n_slots < 8 && (size_t)(n_slots * 2) * SLOT_ELEMS <= avail)
        n_slots *= 2;
    const int slot_mask = n_slots - 1;

    float* P    = (float*)d_ws;
    float* VSUM = P + (size_t)n_slots * SLOT_ELEMS;

    const dim3 grid(N_IG * (B_TOT / B_CHUNK));  // 1024 blocks, swizzled decode
    const dim3 blk(256);
    const int  rs_grid = (B_TOT * JD) / 256;    // 256

    hipMemsetAsync(P, 0, (size_t)n_slots * SLOT_ELEMS * sizeof(float), stream);

    // iter 0: uniform c = 1/32
    caps_fused<0><<<grid, blk, 0, stream>>>(x, W, nullptr, P, slot_mask);
    reduce_squash<<<rs_grid, 256, 0, stream>>>(P, n_slots, VSUM, out, 0, 1);

    // iter 1: logits = hat . v0
    caps_fused<1><<<grid, blk, 0, stream>>>(x, W, VSUM, P, slot_mask);
    reduce_squash<<<rs_grid, 256, 0, stream>>>(P, n_slots, VSUM, out, 1, 1);

    // iter 2: logits = hat . (v0+v1)
    caps_fused<1><<<grid, blk, 0, stream>>>(x, W, VSUM, P, slot_mask);
    reduce_squash<<<rs_grid, 256, 0, stream>>>(P, n_slots, VSUM, out, 2, 0);
}